// Round 2
// baseline (997.813 us; speedup 1.0000x reference)
//
#include <hip/hip_runtime.h>

#define BB 4096
#define SS 512
#define NG 256     // 4*HID gate columns
#define BT 8       // batch rows per workgroup
#define CH 32      // time-chunk length
#define HSTR 72    // hbuf row stride (shorts), 144 B (16-aligned, ~free conflicts)
#define PSTR 40    // pcx row stride (shorts), 80 B (16-aligned)
#define SBSTR 264  // sbias row stride (floats)

typedef __bf16 bf16_t;
typedef bf16_t bf16x8 __attribute__((ext_vector_type(8)));
typedef float  f32x4  __attribute__((ext_vector_type(4)));

__device__ __forceinline__ unsigned short f2bf(float x) {
    union { float f; unsigned u; } q{x};
    unsigned r = (q.u + 0x7fffu + ((q.u >> 16) & 1u)) >> 16;
    return (unsigned short)r;
}
__device__ __forceinline__ float bf2f(unsigned short s) {
    union { unsigned u; float f; } q{((unsigned)s) << 16};
    return q.f;
}
__device__ __forceinline__ float sigmoid_(float x) { return 1.0f / (1.0f + __expf(-x)); }
__device__ __forceinline__ float tanh_(float x)    { return 2.0f / (1.0f + __expf(-2.0f * x)) - 1.0f; }
__device__ __forceinline__ float softplus_(float x){ return x > 20.0f ? x : __logf(1.0f + __expf(x)); }

// K-slot layout (96): 0..63 = h, 64 = prev, 65..74 = cov, 75 = prev residual, 76..95 = 0.
// Chunks 0,1 (slots 0..63) read hbuf; chunk 2 (64..95) reads the precomputed pcx
// (slots 12..31 of each pcx row are zeroed once at setup and never rewritten).
__global__ __launch_bounds__(256, 2)
void deepar_kernel(const float* __restrict__ target, const float* __restrict__ cov,
                   const int* __restrict__ cats, const float* __restrict__ scale,
                   const float* __restrict__ emb0, const float* __restrict__ emb1,
                   const float* __restrict__ emb2, const float* __restrict__ emb3,
                   const float* __restrict__ w_ih, const float* __restrict__ w_hh,
                   const float* __restrict__ bias, const float* __restrict__ w_out,
                   const float* __restrict__ b_out, float* __restrict__ out)
{
    __shared__ __attribute__((aligned(16))) unsigned short pcx[2][CH][BT][PSTR]; // 40960 B
    __shared__ __attribute__((aligned(16))) unsigned short hbuf[2][BT][HSTR];    //  2304 B
    __shared__ float sbias[BT * SBSTR];                                          //  8448 B
    __shared__ float sx[BT * 68];                                                //  2176 B
    __shared__ float obuf[2][CH][20];                                            //  5120 B
    __shared__ float inv_s[BT], scl_s[BT];

    const int tid  = threadIdx.x;
    const int b0   = blockIdx.x * BT;
    const int lane = tid & 63;
    const int wv   = tid >> 6;
    const int qd   = lane >> 4;
    const int ln   = lane & 15;
    const int hrow = ln & 7;          // A-row clamp: rows 8-15 broadcast 0-7

    // ---------------- setup ----------------
    for (int i = tid; i < 2 * BT * HSTR; i += 256) ((unsigned short*)hbuf)[i] = 0;
    for (int i = tid; i < 2 * CH * BT * PSTR; i += 256) ((unsigned short*)pcx)[i] = 0;
    if (tid < BT) {
        float s = scale[b0 + tid];
        scl_s[tid] = s;
        inv_s[tid] = 1.0f / fmaxf(s, 1e-4f);
        sx[tid * 68 + 64] = log1pf(s);
    }
    if (tid < BT * 4) {
        int r = tid >> 2, e = tid & 3;
        int c = cats[(b0 + r) * 4 + e];
        const float* eb = (e == 0 ? emb0 : e == 1 ? emb1 : e == 2 ? emb2 : emb3);
        for (int j = 0; j < 16; ++j) sx[r * 68 + e * 16 + j] = eb[c * 16 + j];
    }
    __syncthreads();

    // sbias[r][n] = bias[n] + static_x[r] . w_ih[11..75][n]
    {
        float bj = bias[tid];
        float acc[BT];
        #pragma unroll
        for (int r = 0; r < BT; ++r) acc[r] = bj;
        for (int k = 0; k < 65; ++k) {
            float w = w_ih[(11 + k) * NG + tid];
            #pragma unroll
            for (int r = 0; r < BT; ++r) acc[r] += sx[r * 68 + k] * w;
        }
        #pragma unroll
        for (int r = 0; r < BT; ++r) sbias[r * SBSTR + tid] = acc[r];
    }

    // chunk 0 of pcx (steps 0..31)
    {
        int row = tid >> 5, i5 = tid & 31;
        const float* cr = cov + (size_t)(b0 + row) * SS * 10;
        #pragma unroll
        for (int j = 0; j < 10; ++j) {
            int e = i5 + 32 * j, tp = e / 10, k = e - 10 * tp;
            pcx[0][tp][row][1 + k] = f2bf(cr[e]);
        }
        float pv = (i5 == 0) ? 0.0f : target[(b0 + row) * SS + i5 - 1] * inv_s[row];
        unsigned short m = f2bf(pv);
        pcx[0][i5][row][0]  = m;
        pcx[0][i5][row][11] = f2bf(pv - bf2f(m));
    }
    __syncthreads();

    // ---------------- register-resident weights ----------------
    bf16x8 bfrag[4][3];
    f32x4  sbf[4];
    #pragma unroll
    for (int ti = 0; ti < 4; ++ti) {
        int n = ln + 16 * (wv + 4 * ti);   // gate ti, unit 16*wv+ln
        #pragma unroll
        for (int c = 0; c < 3; ++c) {
            #pragma unroll
            for (int j = 0; j < 8; ++j) {
                int k = qd * 8 + 32 * c + j;
                float w;
                if (k < 64)                 w = w_hh[k * NG + n];
                else if (k == 64 || k == 75) w = w_ih[n];
                else if (k <= 74)           w = w_ih[(k - 64) * NG + n];
                else                        w = 0.0f;
                bfrag[ti][c][j] = (bf16_t)w;
            }
        }
        #pragma unroll
        for (int r = 0; r < 4; ++r)
            sbf[ti][r] = sbias[((qd * 4 + r) & 7) * SBSTR + n];
    }

    // output head mapping
    const int prow = tid >> 4, po = (tid >> 3) & 1, pkg = tid & 7;
    float wo[8];
    #pragma unroll
    for (int j = 0; j < 8; ++j) wo[j] = w_out[(pkg * 8 + j) * 2 + po];
    const float bo   = b_out[po];
    const float pscl = (po == 0) ? scl_s[prow & 7] : 1.0f;
    const int   opslot = po * 8 + (prow & 7);

    float cst[4] = {0.0f, 0.0f, 0.0f, 0.0f};
    float crg[10];
    float trg = 0.0f;
    #pragma unroll
    for (int j = 0; j < 10; ++j) crg[j] = 0.0f;

    // ---------------- time loop ----------------
    for (int t = 0; t < SS; ++t) {
        const int cur = t & 1, nxt = cur ^ 1;
        __syncthreads();

        // chunk start: issue global loads for chunk c+1 (consumed 16 steps later)
        if ((t & 31) == 0 && t < 480) {
            int row = tid >> 5, i5 = tid & 31, t0n = t + CH;
            const float* cr = cov + (size_t)(b0 + row) * SS * 10 + t0n * 10;
            #pragma unroll
            for (int j = 0; j < 10; ++j) crg[j] = cr[i5 + 32 * j];
            trg = target[(b0 + row) * SS + t0n + i5 - 1];
        }

        // A fragments
        const unsigned short* hb = &hbuf[cur][hrow][0];
        bf16x8 a0 = *(const bf16x8*)(hb + qd * 8);
        bf16x8 a1 = *(const bf16x8*)(hb + 32 + qd * 8);
        bf16x8 a2 = *(const bf16x8*)(&pcx[(t >> 5) & 1][t & 31][hrow][qd * 8]);

        f32x4 acc0 = __builtin_amdgcn_mfma_f32_16x16x32_bf16(a0, bfrag[0][0], sbf[0], 0, 0, 0);
        f32x4 acc1 = __builtin_amdgcn_mfma_f32_16x16x32_bf16(a0, bfrag[1][0], sbf[1], 0, 0, 0);
        f32x4 acc2 = __builtin_amdgcn_mfma_f32_16x16x32_bf16(a0, bfrag[2][0], sbf[2], 0, 0, 0);
        f32x4 acc3 = __builtin_amdgcn_mfma_f32_16x16x32_bf16(a0, bfrag[3][0], sbf[3], 0, 0, 0);
        acc0 = __builtin_amdgcn_mfma_f32_16x16x32_bf16(a1, bfrag[0][1], acc0, 0, 0, 0);
        acc1 = __builtin_amdgcn_mfma_f32_16x16x32_bf16(a1, bfrag[1][1], acc1, 0, 0, 0);
        acc2 = __builtin_amdgcn_mfma_f32_16x16x32_bf16(a1, bfrag[2][1], acc2, 0, 0, 0);
        acc3 = __builtin_amdgcn_mfma_f32_16x16x32_bf16(a1, bfrag[3][1], acc3, 0, 0, 0);
        acc0 = __builtin_amdgcn_mfma_f32_16x16x32_bf16(a2, bfrag[0][2], acc0, 0, 0, 0);
        acc1 = __builtin_amdgcn_mfma_f32_16x16x32_bf16(a2, bfrag[1][2], acc1, 0, 0, 0);
        acc2 = __builtin_amdgcn_mfma_f32_16x16x32_bf16(a2, bfrag[2][2], acc2, 0, 0, 0);
        acc3 = __builtin_amdgcn_mfma_f32_16x16x32_bf16(a2, bfrag[3][2], acc3, 0, 0, 0);

        // output head for step t-1 (waves 0-1 only; rows 0-7)
        if (t > 0 && tid < 128) {
            const unsigned short* xb = &hbuf[cur][prow][pkg * 8];
            bf16x8 hv = *(const bf16x8*)xb;
            float p = 0.0f;
            #pragma unroll
            for (int j = 0; j < 8; ++j) p += (float)hv[j] * wo[j];
            p += __shfl_xor(p, 1);
            p += __shfl_xor(p, 2);
            p += __shfl_xor(p, 4);
            if (pkg == 0) {
                float sp = softplus_(p + bo) + 1e-4f;
                obuf[((t - 1) >> 5) & 1][(t - 1) & 31][opslot] = sp * pscl;
            }
        }

        // mid-chunk: commit next pcx chunk from registers; flush prev obuf chunk
        if ((t & 31) == 16) {
            int c = t >> 5;
            if (c < 15) {
                int row = tid >> 5, i5 = tid & 31, nb = (c + 1) & 1;
                float pv = trg * inv_s[row];
                unsigned short m = f2bf(pv);
                pcx[nb][i5][row][0]  = m;
                pcx[nb][i5][row][11] = f2bf(pv - bf2f(m));
                #pragma unroll
                for (int j = 0; j < 10; ++j) {
                    int e = i5 + 32 * j, tp = e / 10, k = e - 10 * tp;
                    pcx[nb][tp][row][1 + k] = f2bf(crg[j]);
                }
            }
            if (c >= 1) {
                int pb = (c - 1) & 1, t0p = (c - 1) << 5;
                #pragma unroll
                for (int h = 0; h < 2; ++h) {
                    int e = tid + 256 * h;
                    int pe = e >> 8, rowe = (e >> 5) & 7, tte = e & 31;
                    out[(pe ? (BB * SS) : 0) + (b0 + rowe) * SS + t0p + tte] =
                        obuf[pb][tte][pe * 8 + rowe];
                }
            }
        }

        // LSTM cell: lanes 0-31 hold valid rows 0-7 (qd<2)
        if (lane < 32) {
            const int u = 16 * wv + ln;
            #pragma unroll
            for (int r = 0; r < 4; ++r) {
                float ig = sigmoid_(acc0[r]);
                float fg = sigmoid_(acc1[r]);
                float gg = tanh_(acc2[r]);
                float og = sigmoid_(acc3[r]);
                float cc = fg * cst[r] + ig * gg;
                cst[r] = cc;
                hbuf[nxt][qd * 4 + r][u] = f2bf(og * tanh_(cc));
            }
        }
    }

    // ---------------- epilogue ----------------
    __syncthreads();
    if (tid < 128) {   // project t = 511 from hbuf[0]
        const unsigned short* xb = &hbuf[0][prow][pkg * 8];
        bf16x8 hv = *(const bf16x8*)xb;
        float p = 0.0f;
        #pragma unroll
        for (int j = 0; j < 8; ++j) p += (float)hv[j] * wo[j];
        p += __shfl_xor(p, 1);
        p += __shfl_xor(p, 2);
        p += __shfl_xor(p, 4);
        if (pkg == 0) {
            float sp = softplus_(p + bo) + 1e-4f;
            obuf[1][31][opslot] = sp * pscl;
        }
    }
    __syncthreads();
    {   // flush chunk 15
        #pragma unroll
        for (int h = 0; h < 2; ++h) {
            int e = tid + 256 * h;
            int pe = e >> 8, rowe = (e >> 5) & 7, tte = e & 31;
            out[(pe ? (BB * SS) : 0) + (b0 + rowe) * SS + 480 + tte] =
                obuf[1][tte][pe * 8 + rowe];
        }
    }
}

extern "C" void kernel_launch(void* const* d_in, const int* in_sizes, int n_in,
                              void* d_out, int out_size, void* d_ws, size_t ws_size,
                              hipStream_t stream) {
    deepar_kernel<<<BB / BT, 256, 0, stream>>>(
        (const float*)d_in[0], (const float*)d_in[1], (const int*)d_in[2],
        (const float*)d_in[3], (const float*)d_in[4], (const float*)d_in[5],
        (const float*)d_in[6], (const float*)d_in[7], (const float*)d_in[8],
        (const float*)d_in[9], (const float*)d_in[10], (const float*)d_in[11],
        (const float*)d_in[12], (float*)d_out);
}

// Round 3
// 616.101 us; speedup vs baseline: 1.6196x; 1.6196x over previous
//
#include <hip/hip_runtime.h>

#define BB 4096
#define SS 512
#define NG 256     // 4*HID gate columns
#define BT 16      // batch rows per workgroup (grid = 256 = #CUs)
#define CH 32      // time-chunk length
#define HSTR 68    // hbuf row stride (shorts): 16B-aligned, h-writes spread all 32 banks
#define PSTR 16    // pcx row stride (shorts): slots 0..11 real, 12..15 zero
#define SBSTR 264  // sbias row stride (floats)
#define OSTR 33    // obuf row stride (floats): breaks 32-stride conflict on flush

typedef __bf16 bf16_t;
typedef bf16_t bf16x8 __attribute__((ext_vector_type(8)));
typedef float  f32x4  __attribute__((ext_vector_type(4)));

__device__ __forceinline__ unsigned short f2bf(float x) {
    union { float f; unsigned u; } q{x};
    unsigned r = (q.u + 0x7fffu + ((q.u >> 16) & 1u)) >> 16;
    return (unsigned short)r;
}
__device__ __forceinline__ float bf2f(unsigned short s) {
    union { unsigned u; float f; } q{((unsigned)s) << 16};
    return q.f;
}
#define LOG2E 1.4426950408889634f
__device__ __forceinline__ float frcp_(float x)  { return __builtin_amdgcn_rcpf(x); }
__device__ __forceinline__ float fexp2_(float x) { return __builtin_amdgcn_exp2f(x); }
__device__ __forceinline__ float flog2_(float x) { return __builtin_amdgcn_logf(x); }
__device__ __forceinline__ float sigmoid_(float x) { return frcp_(1.0f + fexp2_(-LOG2E * x)); }
__device__ __forceinline__ float tanh_(float x)    { return 1.0f - 2.0f * frcp_(1.0f + fexp2_((2.0f * LOG2E) * x)); }
__device__ __forceinline__ float softplus_(float x){ return x > 20.0f ? x : 0.6931471805599453f * flog2_(1.0f + fexp2_(LOG2E * x)); }

// K-slot layout (96): 0..63 = h, 64 = prev, 65..74 = cov, 75 = prev residual, 76..95 = 0.
// MFMA K-chunks 0,1 read hbuf; chunk 2 reads pcx slots 0..15 (qd 0,1) or zero (qd 2,3).
__global__ __launch_bounds__(256)
void deepar_kernel(const float* __restrict__ target, const float* __restrict__ cov,
                   const int* __restrict__ cats, const float* __restrict__ scale,
                   const float* __restrict__ emb0, const float* __restrict__ emb1,
                   const float* __restrict__ emb2, const float* __restrict__ emb3,
                   const float* __restrict__ w_ih, const float* __restrict__ w_hh,
                   const float* __restrict__ bias, const float* __restrict__ w_out,
                   const float* __restrict__ b_out, float* __restrict__ out)
{
    // pcx (2*32*16*16 shorts = 32768 B) overlays sbias(16896 B)+sx(4352 B) scratch
    __shared__ __attribute__((aligned(16))) unsigned char smemA[2 * CH * BT * PSTR * 2];
    __shared__ __attribute__((aligned(16))) unsigned short hbuf[2][BT][HSTR]; // 4352 B
    __shared__ float obuf[2][CH][OSTR];                                       // 8448 B
    __shared__ float inv_s[BT], scl_s[BT];

    unsigned short* pcx   = (unsigned short*)smemA;
    float*          sbias = (float*)smemA;
    float*          sx    = (float*)(smemA + BT * SBSTR * 4);

    const int tid  = threadIdx.x;
    const int b0   = blockIdx.x * BT;
    const int lane = tid & 63;
    const int wv   = tid >> 6;
    const int qd   = lane >> 4;
    const int ln   = lane & 15;

    // ---------------- setup ----------------
    for (int i = tid; i < 2 * BT * HSTR; i += 256) ((unsigned short*)hbuf)[i] = 0;
    if (tid < BT) {
        float s = scale[b0 + tid];
        scl_s[tid] = s;
        inv_s[tid] = 1.0f / fmaxf(s, 1e-4f);
        sx[tid * 68 + 64] = log1pf(s);
    }
    if (tid < BT * 4) {
        int r = tid >> 2, e = tid & 3;
        int c = cats[(b0 + r) * 4 + e];
        const float* eb = (e == 0 ? emb0 : e == 1 ? emb1 : e == 2 ? emb2 : emb3);
        for (int j = 0; j < 16; ++j) sx[r * 68 + e * 16 + j] = eb[c * 16 + j];
    }
    __syncthreads();

    // sbias[r][n] = bias[n] + static_x[r] . w_ih[11..75][n]   (n = tid)
    {
        float bj = bias[tid];
        float acc[BT];
        #pragma unroll
        for (int r = 0; r < BT; ++r) acc[r] = bj;
        for (int k = 0; k < 65; ++k) {
            float w = w_ih[(11 + k) * NG + tid];
            #pragma unroll
            for (int r = 0; r < BT; ++r) acc[r] += sx[r * 68 + k] * w;
        }
        #pragma unroll
        for (int r = 0; r < BT; ++r) sbias[r * SBSTR + tid] = acc[r];
    }
    __syncthreads();

    // ---------------- register-resident weights + sbias fragments ----------------
    bf16x8 bfrag[4][3];
    f32x4  sbf[4];
    #pragma unroll
    for (int ti = 0; ti < 4; ++ti) {
        int n = ln + 16 * (wv + 4 * ti);   // gate ti, unit 16*wv+ln
        #pragma unroll
        for (int c = 0; c < 3; ++c) {
            #pragma unroll
            for (int j = 0; j < 8; ++j) {
                int k = qd * 8 + 32 * c + j;
                float w;
                if (k < 64)                  w = w_hh[k * NG + n];
                else if (k == 64 || k == 75) w = w_ih[n];
                else if (k <= 74)            w = w_ih[(k - 64) * NG + n];
                else                         w = 0.0f;
                bfrag[ti][c][j] = (bf16_t)w;
            }
        }
        #pragma unroll
        for (int r = 0; r < 4; ++r)
            sbf[ti][r] = sbias[(qd * 4 + r) * SBSTR + n];
    }

    // output head mapping (all 256 threads: 16 rows x 2 outputs x 8 k-groups)
    const int prow = tid >> 4, po = (tid >> 3) & 1, pkg = tid & 7;
    float wo[8];
    #pragma unroll
    for (int j = 0; j < 8; ++j) wo[j] = w_out[(pkg * 8 + j) * 2 + po];
    const float bo     = b_out[po];
    const float pscl   = (po == 0) ? scl_s[prow] : 1.0f;
    const int   opslot = po * 16 + prow;

    __syncthreads();   // all sbias/sx reads done -> safe to overwrite with pcx

    // zero pcx (both buffers; establishes the permanent-zero slots 12..15)
    for (int i = tid; i < (2 * CH * BT * PSTR) / 2; i += 256) ((int*)smemA)[i] = 0;
    __syncthreads();

    // fill pcx chunk 0 (steps 0..31)
    {
        const int row = tid >> 4, i5 = tid & 15;
        const float* cr = cov + (size_t)(b0 + row) * (SS * 10);
        #pragma unroll
        for (int j = 0; j < 20; ++j) {
            int e = i5 + 16 * j, tp = e / 10, k = e - 10 * tp;
            pcx[((0 * CH + tp) * BT + row) * PSTR + 1 + k] = f2bf(cr[e]);
        }
        float pv0 = (i5 == 0) ? 0.0f : target[(size_t)(b0 + row) * SS + i5 - 1] * inv_s[row];
        float pv1 = target[(size_t)(b0 + row) * SS + i5 + 15] * inv_s[row];
        unsigned short m0 = f2bf(pv0), m1 = f2bf(pv1);
        pcx[((0 * CH + i5) * BT + row) * PSTR + 0]        = m0;
        pcx[((0 * CH + i5) * BT + row) * PSTR + 11]       = f2bf(pv0 - bf2f(m0));
        pcx[((0 * CH + i5 + 16) * BT + row) * PSTR + 0]   = m1;
        pcx[((0 * CH + i5 + 16) * BT + row) * PSTR + 11]  = f2bf(pv1 - bf2f(m1));
    }

    float cst[4] = {0.0f, 0.0f, 0.0f, 0.0f};
    float crg[20];
    #pragma unroll
    for (int j = 0; j < 20; ++j) crg[j] = 0.0f;
    float trg0 = 0.0f, trg1 = 0.0f;

    // ---------------- time loop ----------------
    for (int t = 0; t < SS; ++t) {
        const int cur = t & 1, nxt = cur ^ 1;
        __syncthreads();

        // chunk start: issue global loads for chunk c+1 (committed 16 steps later)
        if ((t & 31) == 0 && t < 480) {
            const int row = tid >> 4, i5 = tid & 15, t0n = t + CH;
            const float* cr = cov + (size_t)(b0 + row) * (SS * 10) + t0n * 10;
            #pragma unroll
            for (int j = 0; j < 20; ++j) crg[j] = cr[i5 + 16 * j];
            const float* tr = target + (size_t)(b0 + row) * SS + t0n + i5;
            trg0 = tr[-1];
            trg1 = tr[15];
        }

        // A fragments
        const unsigned short* hb = &hbuf[cur][ln][0];
        bf16x8 a0 = *(const bf16x8*)(hb + qd * 8);
        bf16x8 a1 = *(const bf16x8*)(hb + 32 + qd * 8);
        bf16x8 a2 = {};
        if (qd < 2)
            a2 = *(const bf16x8*)&pcx[((((t >> 5) & 1) * CH + (t & 31)) * BT + ln) * PSTR + qd * 8];

        f32x4 acc0 = __builtin_amdgcn_mfma_f32_16x16x32_bf16(a0, bfrag[0][0], sbf[0], 0, 0, 0);
        f32x4 acc1 = __builtin_amdgcn_mfma_f32_16x16x32_bf16(a0, bfrag[1][0], sbf[1], 0, 0, 0);
        f32x4 acc2 = __builtin_amdgcn_mfma_f32_16x16x32_bf16(a0, bfrag[2][0], sbf[2], 0, 0, 0);
        f32x4 acc3 = __builtin_amdgcn_mfma_f32_16x16x32_bf16(a0, bfrag[3][0], sbf[3], 0, 0, 0);
        acc0 = __builtin_amdgcn_mfma_f32_16x16x32_bf16(a1, bfrag[0][1], acc0, 0, 0, 0);
        acc1 = __builtin_amdgcn_mfma_f32_16x16x32_bf16(a1, bfrag[1][1], acc1, 0, 0, 0);
        acc2 = __builtin_amdgcn_mfma_f32_16x16x32_bf16(a1, bfrag[2][1], acc2, 0, 0, 0);
        acc3 = __builtin_amdgcn_mfma_f32_16x16x32_bf16(a1, bfrag[3][1], acc3, 0, 0, 0);
        acc0 = __builtin_amdgcn_mfma_f32_16x16x32_bf16(a2, bfrag[0][2], acc0, 0, 0, 0);
        acc1 = __builtin_amdgcn_mfma_f32_16x16x32_bf16(a2, bfrag[1][2], acc1, 0, 0, 0);
        acc2 = __builtin_amdgcn_mfma_f32_16x16x32_bf16(a2, bfrag[2][2], acc2, 0, 0, 0);
        acc3 = __builtin_amdgcn_mfma_f32_16x16x32_bf16(a2, bfrag[3][2], acc3, 0, 0, 0);

        // output head for step t-1 (reads previous h; overlaps MFMA latency)
        if (t > 0) {
            bf16x8 hv = *(const bf16x8*)&hbuf[cur][prow][pkg * 8];
            float p = 0.0f;
            #pragma unroll
            for (int j = 0; j < 8; ++j) p += (float)hv[j] * wo[j];
            p += __shfl_xor(p, 1);
            p += __shfl_xor(p, 2);
            p += __shfl_xor(p, 4);
            if (pkg == 0) {
                float sp = softplus_(p + bo) + 1e-4f;
                obuf[((t - 1) >> 5) & 1][(t - 1) & 31][opslot] = sp * pscl;
            }
        }

        // mid-chunk: commit next pcx chunk from registers; flush previous obuf chunk
        if ((t & 31) == 16) {
            const int c = t >> 5;
            if (c < 15) {
                const int row = tid >> 4, i5 = tid & 15, nb = (c + 1) & 1;
                float pv0 = trg0 * inv_s[row];
                float pv1 = trg1 * inv_s[row];
                unsigned short m0 = f2bf(pv0), m1 = f2bf(pv1);
                pcx[((nb * CH + i5) * BT + row) * PSTR + 0]       = m0;
                pcx[((nb * CH + i5) * BT + row) * PSTR + 11]      = f2bf(pv0 - bf2f(m0));
                pcx[((nb * CH + i5 + 16) * BT + row) * PSTR + 0]  = m1;
                pcx[((nb * CH + i5 + 16) * BT + row) * PSTR + 11] = f2bf(pv1 - bf2f(m1));
                #pragma unroll
                for (int j = 0; j < 20; ++j) {
                    int e = i5 + 16 * j, tp = e / 10, k = e - 10 * tp;
                    pcx[((nb * CH + tp) * BT + row) * PSTR + 1 + k] = f2bf(crg[j]);
                }
            }
            if (c >= 1) {
                const int pb = (c - 1) & 1, t0p = (c - 1) << 5;
                #pragma unroll
                for (int h = 0; h < 4; ++h) {
                    int e = tid + 256 * h;
                    int tte = e & 31, rowe = (e >> 5) & 15, pe = e >> 9;
                    out[(pe ? (BB * SS) : 0) + (size_t)(b0 + rowe) * SS + t0p + tte] =
                        obuf[pb][tte][pe * 16 + rowe];
                }
            }
        }

        // lane-local LSTM cell: lane owns unit u = 16*wv+ln, rows qd*4+r
        const int u = 16 * wv + ln;
        #pragma unroll
        for (int r = 0; r < 4; ++r) {
            float ig = sigmoid_(acc0[r]);
            float fg = sigmoid_(acc1[r]);
            float gg = tanh_(acc2[r]);
            float og = sigmoid_(acc3[r]);
            float cc = fg * cst[r] + ig * gg;
            cst[r] = cc;
            hbuf[nxt][qd * 4 + r][u] = f2bf(og * tanh_(cc));
        }
    }

    // ---------------- epilogue: head for t=511 (h in hbuf[0]) + flush chunk 15 ----------------
    __syncthreads();
    {
        bf16x8 hv = *(const bf16x8*)&hbuf[0][prow][pkg * 8];
        float p = 0.0f;
        #pragma unroll
        for (int j = 0; j < 8; ++j) p += (float)hv[j] * wo[j];
        p += __shfl_xor(p, 1);
        p += __shfl_xor(p, 2);
        p += __shfl_xor(p, 4);
        if (pkg == 0) {
            float sp = softplus_(p + bo) + 1e-4f;
            obuf[1][31][opslot] = sp * pscl;
        }
    }
    __syncthreads();
    #pragma unroll
    for (int h = 0; h < 4; ++h) {
        int e = tid + 256 * h;
        int tte = e & 31, rowe = (e >> 5) & 15, pe = e >> 9;
        out[(pe ? (BB * SS) : 0) + (size_t)(b0 + rowe) * SS + 480 + tte] =
            obuf[1][tte][pe * 16 + rowe];
    }
}

extern "C" void kernel_launch(void* const* d_in, const int* in_sizes, int n_in,
                              void* d_out, int out_size, void* d_ws, size_t ws_size,
                              hipStream_t stream) {
    deepar_kernel<<<BB / BT, 256, 0, stream>>>(
        (const float*)d_in[0], (const float*)d_in[1], (const int*)d_in[2],
        (const float*)d_in[3], (const float*)d_in[4], (const float*)d_in[5],
        (const float*)d_in[6], (const float*)d_in[7], (const float*)d_in[8],
        (const float*)d_in[9], (const float*)d_in[10], (const float*)d_in[11],
        (const float*)d_in[12], (float*)d_out);
}